// Round 5
// baseline (79.972 us; speedup 1.0000x reference)
//
#include <hip/hip_runtime.h>
#include <math.h>

// Problem constants (match reference)
#define BB   256
#define KK   16
#define NBIN 128
#define GG   (NBIN * NBIN)     // 16384 bins per batch
#define NT   1024              // threads per block
#define SPT  (GG / NT)         // 16 bins per thread

// ---------------------------------------------------------------------------
// Round-5: wave-uniform mixture culling. Ledger: occupancy x2 null (R1),
// trans -62% null (R2), VALU +160% -> +5us ~nominal (R2), VALU -24% null
// (R4, and expected: scalar v_fma already saturates the FP32 datapath --
// v_pk_fma_f32 doubles FLOPs/instr but holds the datapath 2 passes, so
// packing buys issue slots we don't need). Remaining lever: EVAL COUNT.
// Remap: thread = 1 row x 16 consecutive cols -> wave = contiguous 8x128
// strip. Per (wave, mixture): conservative bound m <= cs*lambda_min*(du^2 +
// dv0^2) (lambda_min of inverse-covariance, precomputed); if no lane's row
// can contribute > 2^-46 * coef (~2e-12, deterministic, <<7.6e-6 absmax and
// <1e-9 relative on the normalizing sum), the whole wave skips the mixture
// (__any -> s_cbranch, no divergence). Narrow Gaussians (sigma~U(0,1)) miss
// most 8-row strips; expected skip ~25-40%. Eval numerics unchanged: same
// direct quadratic fma discipline, roles (du,dv) swapped with the mapping.
// ---------------------------------------------------------------------------

// Trans-pipe exp2 (single v_exp_f32). Argument always <= 0; flush-to-zero
// underflow matches reference exp(-huge) -> 0.
__device__ __forceinline__ float raw_exp2(float x) {
#if __has_builtin(__builtin_amdgcn_exp2f)
    return __builtin_amdgcn_exp2f(x);
#else
    float r;
    asm volatile("v_exp_f32 %0, %1\n\ts_nop 1" : "=v"(r) : "v"(x));
    return r;
#endif
}

// One block per batch (normalization needs the whole batch in one workgroup).
// Thread t owns row r = t>>3, cols c0..c0+15 with c0 = (t&7)*16:
//   du fixed per (thread,k); dv = dvb + e*step (literal-const adds)
//   lane byte address = tid*64 -> stores are contiguous 4KB per wave.
__global__ __launch_bounds__(NT) void gmm_hist_kernel(
    const float* __restrict__ mu,     // [B,K,2]
    const float* __restrict__ sigma,  // [B,K,2]
    const float* __restrict__ cov12,  // [B,K]
    const float* __restrict__ pi_,    // [B,K]
    float* __restrict__ out)          // [B,128,128]
{
    const int b   = blockIdx.x;
    const int tid = threadIdx.x;

    // Per-mixture params packed for ds_read_b128:
    //   s_par[2k+0] = {mu_u, mu_v, ia*cs, 2*ib*cs}
    //   s_par[2k+1] = {ic*cs, coef, L, L*dv0^2}   L = cs*lambda_min <= 0
    __shared__ float4 s_par[2 * KK];
    __shared__ float  s_wsum[NT / 64];
    __shared__ float  s_total;

    // ---- per-mixture precompute (threads 0..15), mirrors reference exactly ----
    if (tid < KK) {
        const int idx = b * KK + tid;
        const float m_u = mu[idx * 2 + 0];
        const float m_v = mu[idx * 2 + 1];
        const float su  = fmaxf(sigma[idx * 2 + 0], 0.001f);
        const float sv  = fmaxf(sigma[idx * 2 + 1], 0.001f);
        const float su2 = su * su;
        const float sv2 = sv * sv;
        const float c11 = su2 + 1e-6f;
        const float c22 = sv2 + 1e-6f;
        const float off = cov12[idx];
        const float det_full = c11 * c22 - off * off;
        const bool  valid    = (det_full > 0.0f);   // NaN compares false -> fallback
        const float det_safe = valid ? det_full : 1.0f;
        const float ia  = valid ? (c22 / det_safe) : (1.0f / su2);
        const float ib  = valid ? (-off / det_safe) : 0.0f;
        const float ic  = valid ? (c11 / det_safe) : (1.0f / sv2);
        const float det = valid ? det_full : (su2 * sv2);
        const float coef = pi_[idx] / (6.283185307179586f * sqrtf(det + 1e-6f));
        const float cs = -0.7213475204444817f;      // -0.5 * log2(e), folded

        // lambda_min of [[ia, ib], [ib, ic]] (PSD up to rounding; clamp >=0
        // keeps the cull bound conservative).
        const float lh   = 0.5f * (ia + ic);
        const float lq   = sqrtf(0.25f * (ia - ic) * (ia - ic) + ib * ib);
        const float lmin = fmaxf(lh - lq, 0.0f);
        const float L    = lmin * cs;               // <= 0
        // min |dv| over the grid (0 if mu_v inside [-2,2]); conservative.
        const float dv0  = fmaxf(fabsf(m_v) - 2.0f, 0.0f);

        s_par[2 * tid + 0] = make_float4(m_u, m_v, ia * cs, (2.0f * ib) * cs);
        s_par[2 * tid + 1] = make_float4(ic * cs, coef, L, L * dv0 * dv0);
    }
    __syncthreads();

    const float step = 4.0f / 127.0f;               // linspace(-2,2,128) step
    const int   r    = tid >> 3;                    // row 0..127
    const int   c0   = (tid & 7) << 4;              // first col (16 per thread)
    const float gu   = -2.0f + (float)r  * step;    // row coord
    const float v0   = -2.0f + (float)c0 * step;    // col coord at e=0

    float acc[SPT];
    #pragma unroll
    for (int e = 0; e < SPT; ++e) acc[e] = 0.0f;

    // ---- main accumulation: 16 mixtures x 16 bins per thread ----
    // Per eval: v_add(dv) + v_fma + v_fma + v_exp + v_fma.
    // Direct quadratic-form evaluation (NOT expanded in the index): expanded
    // forms cancel catastrophically for narrow Gaussians (ia up to ~1e6).
    #pragma unroll
    for (int k = 0; k < KK; ++k) {
        const float4 p0 = s_par[2 * k + 0];         // ds_read_b128
        const float4 p1 = s_par[2 * k + 1];         // ds_read_b128
        const float du   = gu - p0.x;               // fixed per (thread,k)
        const float du2  = du * du;

        // Wave-uniform cull: max contribution of k over this lane's row is
        // <= coef * 2^bound; if no lane in the wave exceeds 2^-46, skip.
        const float bound = __builtin_fmaf(p1.z, du2, p1.w);
        if (__any(bound > -46.0f)) {
            const float dvb  = v0 - p0.y;
            const float C2   = p1.x;                // ic*cs
            const float C1   = p0.w * du;           // (2*ib*cs)*du
            const float C0   = p0.z * du2;          // (ia*cs)*du^2
            const float coef = p1.y;

            // Two groups of 8: phase-separated (m -> exp -> acc) so the
            // trans pipe gets batched work and chain temps stay at 8 wide.
            #pragma unroll
            for (int h = 0; h < SPT; h += 8) {
                float m8[8];
                #pragma unroll
                for (int t = 0; t < 8; ++t) {
                    const float dv = dvb + (float)(h + t) * step;         // v_add (lit)
                    const float tt = __builtin_fmaf(C2, dv, C1);          // v_fma
                    m8[t] = __builtin_fmaf(dv, tt, C0);                   // v_fma (<= 0)
                }
                float e8[8];
                #pragma unroll
                for (int t = 0; t < 8; ++t) e8[t] = raw_exp2(m8[t]);      // v_exp_f32
                #pragma unroll
                for (int t = 0; t < 8; ++t)
                    acc[h + t] = __builtin_fmaf(coef, e8[t], acc[h + t]); // v_fma
            }
        }
    }

    // ---- block-wide sum for per-batch normalization ----
    float local = 0.0f;
    #pragma unroll
    for (int e = 0; e < SPT; ++e) local += acc[e];

    #pragma unroll
    for (int off = 32; off >= 1; off >>= 1)
        local += __shfl_down(local, off, 64);

    const int wave = tid >> 6;
    const int lane = tid & 63;
    if (lane == 0) s_wsum[wave] = local;
    __syncthreads();

    if (tid == 0) {
        float t = 0.0f;
        #pragma unroll
        for (int w = 0; w < NT / 64; ++w) t += s_wsum[w];
        s_total = (t > 0.0f) ? t : 1.0f;                    // ref: where(s>0, s, 1)
    }
    __syncthreads();

    // ---- normalized store: 4 x dwordx4 per thread, contiguous 64B/lane ----
    const float inv = 1.0f / s_total;
    float4* o4 = reinterpret_cast<float4*>(out + (size_t)b * GG + (size_t)tid * SPT);
    #pragma unroll
    for (int q = 0; q < SPT / 4; ++q)
        o4[q] = make_float4(acc[4 * q + 0] * inv, acc[4 * q + 1] * inv,
                            acc[4 * q + 2] * inv, acc[4 * q + 3] * inv);
}

extern "C" void kernel_launch(void* const* d_in, const int* in_sizes, int n_in,
                              void* d_out, int out_size, void* d_ws, size_t ws_size,
                              hipStream_t stream) {
    const float* mu    = (const float*)d_in[0];
    const float* sigma = (const float*)d_in[1];
    const float* cov12 = (const float*)d_in[2];
    const float* pi_   = (const float*)d_in[3];
    float* out = (float*)d_out;

    hipLaunchKernelGGL(gmm_hist_kernel, dim3(BB), dim3(NT), 0, stream,
                       mu, sigma, cov12, pi_, out);
}